// Round 1
// baseline (1131.579 us; speedup 1.0000x reference)
//
#include <hip/hip_runtime.h>

#define N_NODES 100000
#define N_EDGES 3200000
#define N_GRAPHS 64
#define IN_DIM 128
#define HIDDEN 64
#define LATENT 16

// ---------------- degree histogram ----------------
__global__ __launch_bounds__(256) void hist_k(const int* __restrict__ src,
                                              const int* __restrict__ dst,
                                              int* __restrict__ deg_out,
                                              int* __restrict__ deg_in) {
  int i = blockIdx.x * blockDim.x + threadIdx.x;
  int stride = gridDim.x * blockDim.x;
  for (; i < N_EDGES; i += stride) {
    atomicAdd(&deg_out[src[i]], 1);
    atomicAdd(&deg_in[dst[i]], 1);
  }
}

// ---------------- exclusive scan of deg_in -> row_ptr (single block) ----------------
__global__ __launch_bounds__(1024) void scan_k(const int* __restrict__ deg_in,
                                               int* __restrict__ row_ptr) {
  __shared__ int tsum[1024];
  const int T = 1024;
  int t = threadIdx.x;
  int chunk = (N_NODES + T - 1) / T;  // 98
  int start = t * chunk;
  int end = start + chunk; if (end > N_NODES) end = N_NODES;
  int s = 0;
  for (int i = start; i < end && i < N_NODES; i++) s += deg_in[i];
  tsum[t] = s;
  __syncthreads();
  // Hillis-Steele inclusive scan over chunk sums
  for (int off = 1; off < T; off <<= 1) {
    int add = 0;
    if (t >= off) add = tsum[t - off];
    __syncthreads();
    if (t >= off) tsum[t] += add;
    __syncthreads();
  }
  int run = tsum[t] - s;  // exclusive prefix of my chunk
  for (int i = start; i < end && i < N_NODES; i++) {
    row_ptr[i] = run;
    run += deg_in[i];
  }
  if (t == T - 1) row_ptr[N_NODES] = tsum[T - 1];
}

// ---------------- CSR fill (by dst, store src) ----------------
__global__ __launch_bounds__(256) void csr_fill_k(const int* __restrict__ src,
                                                  const int* __restrict__ dst,
                                                  const int* __restrict__ row_ptr,
                                                  int* __restrict__ cursor,
                                                  int* __restrict__ csr_src) {
  int i = blockIdx.x * blockDim.x + threadIdx.x;
  int stride = gridDim.x * blockDim.x;
  for (; i < N_EDGES; i += stride) {
    int d = dst[i];
    int pos = row_ptr[d] + atomicAdd(&cursor[d], 1);
    csr_src[pos] = src[i];
  }
}

// ---------------- GEMM: out[n][c] = (sum_d X[n][d]*W[d][c]) * rsqrt(max(deg_out[n],1)) ----
template <int IN>
__global__ __launch_bounds__(256) void gemm_scale_k(const float* __restrict__ X,
                                                    const float* __restrict__ W,
                                                    const int* __restrict__ deg,
                                                    float* __restrict__ out) {
  __shared__ float ws[IN][HIDDEN];
  __shared__ float xs[4][IN];
  int t = threadIdx.x;
  for (int i = t; i < IN * HIDDEN; i += 256) ws[i / HIDDEN][i % HIDDEN] = W[i];
  int row0 = blockIdx.x * 4;
  for (int i = t; i < 4 * IN; i += 256) {
    int r = row0 + i / IN;
    xs[i / IN][i % IN] = (r < N_NODES) ? X[(size_t)r * IN + (i % IN)] : 0.f;
  }
  __syncthreads();
  int rl = t >> 6, col = t & 63;
  int row = row0 + rl;
  if (row >= N_NODES) return;
  float acc = 0.f;
#pragma unroll
  for (int d = 0; d < IN; d++) acc += xs[rl][d] * ws[d][col];
  float dg = (float)deg[row];
  if (dg < 1.f) dg = 1.f;
  out[(size_t)row * HIDDEN + col] = acc * rsqrtf(dg);
}

// ---------------- aggregate: out[n][c] = relu(rsqrt(deg_in) * sum_{e->n} hw[src_e][c] + b[c]) ----
__global__ __launch_bounds__(256) void aggregate_k(const float* __restrict__ hw,
                                                   const int* __restrict__ row_ptr,
                                                   const int* __restrict__ csr_src,
                                                   const int* __restrict__ deg_in,
                                                   const float* __restrict__ bias,
                                                   float* __restrict__ out) {
  int wave = (int)((blockIdx.x * blockDim.x + threadIdx.x) >> 6);
  int lane = threadIdx.x & 63;
  if (wave >= N_NODES) return;
  int start = row_ptr[wave], end = row_ptr[wave + 1];
  float acc = 0.f;
  int j = start;
  for (; j + 3 < end; j += 4) {
    int s0 = csr_src[j], s1 = csr_src[j + 1], s2 = csr_src[j + 2], s3 = csr_src[j + 3];
    float a0 = hw[(size_t)s0 * HIDDEN + lane];
    float a1 = hw[(size_t)s1 * HIDDEN + lane];
    float a2 = hw[(size_t)s2 * HIDDEN + lane];
    float a3 = hw[(size_t)s3 * HIDDEN + lane];
    acc += (a0 + a1) + (a2 + a3);
  }
  for (; j < end; j++) {
    int s = csr_src[j];
    acc += hw[(size_t)s * HIDDEN + lane];
  }
  float dg = (float)deg_in[wave];
  if (dg < 1.f) dg = 1.f;
  float v = acc * rsqrtf(dg) + bias[lane];
  out[(size_t)wave * HIDDEN + lane] = v > 0.f ? v : 0.f;
}

// ---------------- per-graph mean pool stage 1 (sorted node_graph, run-accumulate) ----------------
__global__ __launch_bounds__(256) void pool_k(const float* __restrict__ h,
                                              const int* __restrict__ node_graph,
                                              float* __restrict__ sums,
                                              float* __restrict__ counts) {
  const int NPW = 256;  // nodes per wave
  int wave = (int)((blockIdx.x * blockDim.x + threadIdx.x) >> 6);
  int lane = threadIdx.x & 63;
  int start = wave * NPW;
  if (start >= N_NODES) return;
  int end = start + NPW; if (end > N_NODES) end = N_NODES;
  int cur = node_graph[start];
  float acc = 0.f, cnt = 0.f;
  for (int n = start; n < end; n++) {
    int g = node_graph[n];
    if (g != cur) {
      atomicAdd(&sums[cur * HIDDEN + lane], acc);
      if (lane == 0) atomicAdd(&counts[cur], cnt);
      cur = g; acc = 0.f; cnt = 0.f;
    }
    acc += h[(size_t)n * HIDDEN + lane];
    cnt += 1.f;
  }
  atomicAdd(&sums[cur * HIDDEN + lane], acc);
  if (lane == 0) atomicAdd(&counts[cur], cnt);
}

// ---------------- final: h_graph = sums/counts; mu/logvar = h_graph @ Wmu/Wlv + b ----------------
__global__ __launch_bounds__(256) void final_k(const float* __restrict__ sums,
                                               const float* __restrict__ counts,
                                               const float* __restrict__ Wmu,
                                               const float* __restrict__ bmu,
                                               const float* __restrict__ Wlv,
                                               const float* __restrict__ blv,
                                               float* __restrict__ out) {
  __shared__ float hg[N_GRAPHS][HIDDEN];
  __shared__ float wmu[HIDDEN][LATENT];
  __shared__ float wlv[HIDDEN][LATENT];
  int t = threadIdx.x;
  for (int i = t; i < N_GRAPHS * HIDDEN; i += 256) {
    int g = i / HIDDEN;
    float c = counts[g];
    if (c < 1.f) c = 1.f;
    hg[g][i % HIDDEN] = sums[i] / c;
  }
  for (int i = t; i < HIDDEN * LATENT; i += 256) {
    wmu[i / LATENT][i % LATENT] = Wmu[i];
    wlv[i / LATENT][i % LATENT] = Wlv[i];
  }
  __syncthreads();
  for (int i = t; i < N_GRAPHS * LATENT; i += 256) {
    int g = i / LATENT, j = i % LATENT;
    float mu = bmu[j], lv = blv[j];
#pragma unroll
    for (int k = 0; k < HIDDEN; k++) {
      float v = hg[g][k];
      mu += v * wmu[k][j];
      lv += v * wlv[k][j];
    }
    out[i] = mu;
    out[N_GRAPHS * LATENT + i] = lv;
  }
}

extern "C" void kernel_launch(void* const* d_in, const int* in_sizes, int n_in,
                              void* d_out, int out_size, void* d_ws, size_t ws_size,
                              hipStream_t stream) {
  const float* x = (const float*)d_in[0];
  // d_in[1] = edge_feat: provably unused for (mu, logvar)
  const int* src = (const int*)d_in[2];
  const int* dst = (const int*)d_in[3];
  const int* node_graph = (const int*)d_in[4];
  const float* W1 = (const float*)d_in[5];
  const float* b1 = (const float*)d_in[6];
  const float* W2 = (const float*)d_in[7];
  const float* b2 = (const float*)d_in[8];
  // d_in[9] = We, d_in[10] = be: unused
  const float* Wmu = (const float*)d_in[11];
  const float* bmu = (const float*)d_in[12];
  const float* Wlv = (const float*)d_in[13];
  const float* blv = (const float*)d_in[14];
  float* out = (float*)d_out;

  char* ws = (char*)d_ws;
  int* deg_out = (int*)(ws);                 // 400000 B (pad 400128)
  int* deg_in  = (int*)(ws + 400128);        // 400000 B
  int* row_ptr = (int*)(ws + 800256);        // 400004 B
  int* cursor  = (int*)(ws + 1200384);       // 400000 B
  int* csr_src = (int*)(ws + 1600512);       // 12800000 B
  float* A     = (float*)(ws + 14400512);    // 25600000 B
  float* B     = (float*)(ws + 40000512);    // 25600000 B
  float* sums  = (float*)(ws + 65600512);    // 16384 B
  float* cnts  = (float*)(ws + 65616896);    // 256 B

  // zero the accumulators we rely on (harness poisons d_ws with 0xAA)
  hipMemsetAsync(deg_out, 0, 400000, stream);
  hipMemsetAsync(deg_in, 0, 400000, stream);
  hipMemsetAsync(cursor, 0, 400000, stream);
  hipMemsetAsync(sums, 0, 16384 + 256, stream);

  hist_k<<<2048, 256, 0, stream>>>(src, dst, deg_out, deg_in);
  scan_k<<<1, 1024, 0, stream>>>(deg_in, row_ptr);
  csr_fill_k<<<2048, 256, 0, stream>>>(src, dst, row_ptr, cursor, csr_src);

  // layer 1: A = (x @ W1) * deg_out^-1/2 ; B = relu(agg(A) * deg_in^-1/2 + b1)
  gemm_scale_k<IN_DIM><<<(N_NODES + 3) / 4, 256, 0, stream>>>(x, W1, deg_out, A);
  aggregate_k<<<(N_NODES + 3) / 4, 256, 0, stream>>>(A, row_ptr, csr_src, deg_in, b1, B);

  // layer 2: A = (B @ W2) * deg_out^-1/2 ; B = relu(agg(A) * deg_in^-1/2 + b2)
  gemm_scale_k<HIDDEN><<<(N_NODES + 3) / 4, 256, 0, stream>>>(B, W2, deg_out, A);
  aggregate_k<<<(N_NODES + 3) / 4, 256, 0, stream>>>(A, row_ptr, csr_src, deg_in, b2, B);

  // pool + heads
  pool_k<<<((N_NODES + 255) / 256 + 3) / 4, 256, 0, stream>>>(B, node_graph, sums, cnts);
  final_k<<<1, 256, 0, stream>>>(sums, cnts, Wmu, bmu, Wlv, blv, out);
}

// Round 2
// 608.615 us; speedup vs baseline: 1.8593x; 1.8593x over previous
//
#include <hip/hip_runtime.h>

#define N_NODES 100000
#define N_EDGES 3200000
#define N_GRAPHS 64
#define IN_DIM 128
#define HIDDEN 64
#define LATENT 16

#define NBUCK 1024
#define BSHIFT 7
#define NODES_PER_BUCK 128
#define NBLK_PART 256
#define NB_USED ((N_NODES + NODES_PER_BUCK - 1) / NODES_PER_BUCK)  // 782

// ---------------- pass A: 1024-bucket histograms of src and dst (LDS-privatized) ----
__global__ __launch_bounds__(256) void bucket_hist_k(const int4* __restrict__ src4,
                                                     const int4* __restrict__ dst4,
                                                     int* __restrict__ bc_src,
                                                     int* __restrict__ bc_dst) {
  __shared__ int hs[NBUCK], hd[NBUCK];
  int t = threadIdx.x;
  for (int i = t; i < NBUCK; i += 256) { hs[i] = 0; hd[i] = 0; }
  __syncthreads();
  const int Q = N_EDGES / 4;          // 800000
  const int QPB = Q / NBLK_PART;      // 3125
  int q0 = blockIdx.x * QPB, q1 = q0 + QPB;
  for (int i = q0 + t; i < q1; i += 256) {
    int4 s = src4[i], d = dst4[i];
    atomicAdd(&hs[s.x >> BSHIFT], 1); atomicAdd(&hs[s.y >> BSHIFT], 1);
    atomicAdd(&hs[s.z >> BSHIFT], 1); atomicAdd(&hs[s.w >> BSHIFT], 1);
    atomicAdd(&hd[d.x >> BSHIFT], 1); atomicAdd(&hd[d.y >> BSHIFT], 1);
    atomicAdd(&hd[d.z >> BSHIFT], 1); atomicAdd(&hd[d.w >> BSHIFT], 1);
  }
  __syncthreads();
  for (int i = t; i < NBUCK; i += 256) {
    if (hs[i]) atomicAdd(&bc_src[i], hs[i]);
    if (hd[i]) atomicAdd(&bc_dst[i], hd[i]);
  }
}

// ---------------- pass B: exclusive scan of both bucket-count arrays ----------------
__global__ __launch_bounds__(1024) void bucket_scan_k(const int* __restrict__ bc_src,
                                                      const int* __restrict__ bc_dst,
                                                      int* __restrict__ bbase_src,
                                                      int* __restrict__ bbase_dst,
                                                      int* __restrict__ row_ptr) {
  __shared__ int a[NBUCK], b[NBUCK];
  int t = threadIdx.x;
  int va = bc_src[t], vb = bc_dst[t];
  a[t] = va; b[t] = vb;
  __syncthreads();
  for (int off = 1; off < NBUCK; off <<= 1) {
    int xa = 0, xb = 0;
    if (t >= off) { xa = a[t - off]; xb = b[t - off]; }
    __syncthreads();
    if (t >= off) { a[t] += xa; b[t] += xb; }
    __syncthreads();
  }
  bbase_src[t] = a[t] - va;
  bbase_dst[t] = b[t] - vb;
  if (t == NBUCK - 1) {
    bbase_src[NBUCK] = a[t];
    bbase_dst[NBUCK] = b[t];
    row_ptr[N_NODES] = N_EDGES;
  }
}

// ---------------- pass C: scatter src stream and packed (ldst,src) stream into buckets ----
__global__ __launch_bounds__(256) void scatter_k(const int4* __restrict__ src4,
                                                 const int4* __restrict__ dst4,
                                                 const int* __restrict__ bbase_src,
                                                 const int* __restrict__ bbase_dst,
                                                 int* __restrict__ cur_src,
                                                 int* __restrict__ cur_dst,
                                                 int* __restrict__ sortedS,
                                                 int* __restrict__ sortedE) {
  __shared__ int hs[NBUCK], hd[NBUCK];
  __shared__ int rs[NBUCK], rd[NBUCK];
  int t = threadIdx.x;
  for (int i = t; i < NBUCK; i += 256) { hs[i] = 0; hd[i] = 0; }
  __syncthreads();
  const int Q = N_EDGES / 4;
  const int QPB = Q / NBLK_PART;
  int q0 = blockIdx.x * QPB, q1 = q0 + QPB;
  for (int i = q0 + t; i < q1; i += 256) {
    int4 s = src4[i], d = dst4[i];
    atomicAdd(&hs[s.x >> BSHIFT], 1); atomicAdd(&hs[s.y >> BSHIFT], 1);
    atomicAdd(&hs[s.z >> BSHIFT], 1); atomicAdd(&hs[s.w >> BSHIFT], 1);
    atomicAdd(&hd[d.x >> BSHIFT], 1); atomicAdd(&hd[d.y >> BSHIFT], 1);
    atomicAdd(&hd[d.z >> BSHIFT], 1); atomicAdd(&hd[d.w >> BSHIFT], 1);
  }
  __syncthreads();
  for (int i = t; i < NBUCK; i += 256) {
    rs[i] = hs[i] ? (atomicAdd(&cur_src[i], hs[i]) + bbase_src[i]) : 0;
    rd[i] = hd[i] ? (atomicAdd(&cur_dst[i], hd[i]) + bbase_dst[i]) : 0;
  }
  __syncthreads();
  for (int i = q0 + t; i < q1; i += 256) {
    int4 s = src4[i], d = dst4[i];
    int sv[4] = {s.x, s.y, s.z, s.w};
    int dv[4] = {d.x, d.y, d.z, d.w};
#pragma unroll
    for (int k = 0; k < 4; k++) {
      int ps = atomicAdd(&rs[sv[k] >> BSHIFT], 1);
      sortedS[ps] = sv[k];
      int pd = atomicAdd(&rd[dv[k] >> BSHIFT], 1);
      sortedE[pd] = ((dv[k] & (NODES_PER_BUCK - 1)) << 17) | sv[k];
    }
  }
}

// ---------------- pass D: per-bucket CSR + degrees (all atomics in LDS) ----------------
__global__ __launch_bounds__(256) void bucket_csr_k(const int* __restrict__ sortedS,
                                                    const int* __restrict__ sortedE,
                                                    const int* __restrict__ bbase_src,
                                                    const int* __restrict__ bbase_dst,
                                                    int* __restrict__ deg_out,
                                                    int* __restrict__ deg_in,
                                                    int* __restrict__ row_ptr,
                                                    int* __restrict__ csr_src) {
  __shared__ int hin[NODES_PER_BUCK], hout[NODES_PER_BUCK];
  __shared__ int scn[NODES_PER_BUCK], cur[NODES_PER_BUCK];
  int bk = blockIdx.x, t = threadIdx.x;
  int node0 = bk << BSHIFT;
  if (t < NODES_PER_BUCK) { hin[t] = 0; hout[t] = 0; cur[t] = 0; }
  __syncthreads();
  int s0 = bbase_src[bk], s1 = bbase_src[bk + 1];
  for (int j = s0 + t; j < s1; j += 256)
    atomicAdd(&hout[sortedS[j] & (NODES_PER_BUCK - 1)], 1);
  int e0 = bbase_dst[bk], e1 = bbase_dst[bk + 1];
  for (int j = e0 + t; j < e1; j += 256)
    atomicAdd(&hin[sortedE[j] >> 17], 1);
  __syncthreads();
  if (t < NODES_PER_BUCK) scn[t] = hin[t];
  __syncthreads();
  for (int off = 1; off < NODES_PER_BUCK; off <<= 1) {
    int v = 0;
    if (t < NODES_PER_BUCK && t >= off) v = scn[t - off];
    __syncthreads();
    if (t < NODES_PER_BUCK && t >= off) scn[t] += v;
    __syncthreads();
  }
  int n = node0 + t;
  if (t < NODES_PER_BUCK && n < N_NODES) {
    deg_out[n] = hout[t];
    deg_in[n] = hin[t];
    row_ptr[n] = e0 + scn[t] - hin[t];
  }
  __syncthreads();
  for (int j = e0 + t; j < e1; j += 256) {
    int v = sortedE[j];
    int ln = v >> 17;
    int pos = e0 + scn[ln] - hin[ln] + atomicAdd(&cur[ln], 1);
    csr_src[pos] = v & 0x1FFFF;
  }
}

// ---------------- GEMM: out[n][c] = (sum_d X[n][d]*W[d][c]) * rsqrt(max(deg_out[n],1)) ----
template <int IN>
__global__ __launch_bounds__(256) void gemm_scale_k(const float* __restrict__ X,
                                                    const float* __restrict__ W,
                                                    const int* __restrict__ deg,
                                                    float* __restrict__ out) {
  __shared__ float ws[IN][HIDDEN];
  __shared__ float xs[4][IN];
  int t = threadIdx.x;
  for (int i = t; i < IN * HIDDEN; i += 256) ws[i / HIDDEN][i % HIDDEN] = W[i];
  int row0 = blockIdx.x * 4;
  for (int i = t; i < 4 * IN; i += 256) {
    int r = row0 + i / IN;
    xs[i / IN][i % IN] = (r < N_NODES) ? X[(size_t)r * IN + (i % IN)] : 0.f;
  }
  __syncthreads();
  int rl = t >> 6, col = t & 63;
  int row = row0 + rl;
  if (row >= N_NODES) return;
  float acc = 0.f;
#pragma unroll
  for (int d = 0; d < IN; d++) acc += xs[rl][d] * ws[d][col];
  float dg = (float)deg[row];
  if (dg < 1.f) dg = 1.f;
  out[(size_t)row * HIDDEN + col] = acc * rsqrtf(dg);
}

// ---------------- aggregate: out[n][c] = relu(rsqrt(deg_in) * sum_{e->n} hw[src_e][c] + b[c]) ----
__global__ __launch_bounds__(256) void aggregate_k(const float* __restrict__ hw,
                                                   const int* __restrict__ row_ptr,
                                                   const int* __restrict__ csr_src,
                                                   const int* __restrict__ deg_in,
                                                   const float* __restrict__ bias,
                                                   float* __restrict__ out) {
  int wave = (int)((blockIdx.x * blockDim.x + threadIdx.x) >> 6);
  int lane = threadIdx.x & 63;
  if (wave >= N_NODES) return;
  int start = row_ptr[wave], end = row_ptr[wave + 1];
  float acc = 0.f;
  int j = start;
  for (; j + 3 < end; j += 4) {
    int s0 = csr_src[j], s1 = csr_src[j + 1], s2 = csr_src[j + 2], s3 = csr_src[j + 3];
    float a0 = hw[(size_t)s0 * HIDDEN + lane];
    float a1 = hw[(size_t)s1 * HIDDEN + lane];
    float a2 = hw[(size_t)s2 * HIDDEN + lane];
    float a3 = hw[(size_t)s3 * HIDDEN + lane];
    acc += (a0 + a1) + (a2 + a3);
  }
  for (; j < end; j++) {
    int s = csr_src[j];
    acc += hw[(size_t)s * HIDDEN + lane];
  }
  float dg = (float)deg_in[wave];
  if (dg < 1.f) dg = 1.f;
  float v = acc * rsqrtf(dg) + bias[lane];
  out[(size_t)wave * HIDDEN + lane] = v > 0.f ? v : 0.f;
}

// ---------------- per-graph mean pool stage 1 (sorted node_graph, run-accumulate) ----------------
__global__ __launch_bounds__(256) void pool_k(const float* __restrict__ h,
                                              const int* __restrict__ node_graph,
                                              float* __restrict__ sums,
                                              float* __restrict__ counts) {
  const int NPW = 256;  // nodes per wave
  int wave = (int)((blockIdx.x * blockDim.x + threadIdx.x) >> 6);
  int lane = threadIdx.x & 63;
  int start = wave * NPW;
  if (start >= N_NODES) return;
  int end = start + NPW; if (end > N_NODES) end = N_NODES;
  int cur = node_graph[start];
  float acc = 0.f, cnt = 0.f;
  for (int n = start; n < end; n++) {
    int g = node_graph[n];
    if (g != cur) {
      atomicAdd(&sums[cur * HIDDEN + lane], acc);
      if (lane == 0) atomicAdd(&counts[cur], cnt);
      cur = g; acc = 0.f; cnt = 0.f;
    }
    acc += h[(size_t)n * HIDDEN + lane];
    cnt += 1.f;
  }
  atomicAdd(&sums[cur * HIDDEN + lane], acc);
  if (lane == 0) atomicAdd(&counts[cur], cnt);
}

// ---------------- final: h_graph = sums/counts; mu/logvar = h_graph @ Wmu/Wlv + b ----------------
__global__ __launch_bounds__(256) void final_k(const float* __restrict__ sums,
                                               const float* __restrict__ counts,
                                               const float* __restrict__ Wmu,
                                               const float* __restrict__ bmu,
                                               const float* __restrict__ Wlv,
                                               const float* __restrict__ blv,
                                               float* __restrict__ out) {
  __shared__ float hg[N_GRAPHS][HIDDEN];
  __shared__ float wmu[HIDDEN][LATENT];
  __shared__ float wlv[HIDDEN][LATENT];
  int t = threadIdx.x;
  for (int i = t; i < N_GRAPHS * HIDDEN; i += 256) {
    int g = i / HIDDEN;
    float c = counts[g];
    if (c < 1.f) c = 1.f;
    hg[g][i % HIDDEN] = sums[i] / c;
  }
  for (int i = t; i < HIDDEN * LATENT; i += 256) {
    wmu[i / LATENT][i % LATENT] = Wmu[i];
    wlv[i / LATENT][i % LATENT] = Wlv[i];
  }
  __syncthreads();
  for (int i = t; i < N_GRAPHS * LATENT; i += 256) {
    int g = i / LATENT, j = i % LATENT;
    float mu = bmu[j], lv = blv[j];
#pragma unroll
    for (int k = 0; k < HIDDEN; k++) {
      float v = hg[g][k];
      mu += v * wmu[k][j];
      lv += v * wlv[k][j];
    }
    out[i] = mu;
    out[N_GRAPHS * LATENT + i] = lv;
  }
}

extern "C" void kernel_launch(void* const* d_in, const int* in_sizes, int n_in,
                              void* d_out, int out_size, void* d_ws, size_t ws_size,
                              hipStream_t stream) {
  const float* x = (const float*)d_in[0];
  // d_in[1] = edge_feat: provably unused for (mu, logvar)
  const int* src = (const int*)d_in[2];
  const int* dst = (const int*)d_in[3];
  const int* node_graph = (const int*)d_in[4];
  const float* W1 = (const float*)d_in[5];
  const float* b1 = (const float*)d_in[6];
  const float* W2 = (const float*)d_in[7];
  const float* b2 = (const float*)d_in[8];
  // d_in[9] = We, d_in[10] = be: unused
  const float* Wmu = (const float*)d_in[11];
  const float* bmu = (const float*)d_in[12];
  const float* Wlv = (const float*)d_in[13];
  const float* blv = (const float*)d_in[14];
  float* out = (float*)d_out;

  char* ws = (char*)d_ws;
  // zeroed control block [0, 33280)
  int* bc_src   = (int*)(ws + 0);        // 4096
  int* bc_dst   = (int*)(ws + 4096);     // 4096
  int* cur_src  = (int*)(ws + 8192);     // 4096
  int* cur_dst  = (int*)(ws + 12288);    // 4096
  float* cnts   = (float*)(ws + 16384);  // 256 (pad 512)
  float* sums   = (float*)(ws + 16896);  // 16384
  // non-zeroed control
  int* bbase_src = (int*)(ws + 33280);   // 4100
  int* bbase_dst = (int*)(ws + 37632);   // 4100
  // big arrays
  int* deg_out = (int*)(ws + 65536);     // 400000 (pad 400128)
  int* deg_in  = (int*)(ws + 465664);    // 400000
  int* row_ptr = (int*)(ws + 865792);    // 400004
  int* csr_src = (int*)(ws + 1266176);   // 12800000
  int* sortedS = (int*)(ws + 14066176);  // 12800000 } dead after bucket_csr_k,
  int* sortedE = (int*)(ws + 26866176);  // 12800000 } region reused as A
  float* A     = (float*)(ws + 14066176);// 25600000 (alias of sortedS+sortedE)
  float* B     = (float*)(ws + 39666176);// 25600000 → end 65266176

  hipMemsetAsync(ws, 0, 33280, stream);

  bucket_hist_k<<<NBLK_PART, 256, 0, stream>>>((const int4*)src, (const int4*)dst,
                                               bc_src, bc_dst);
  bucket_scan_k<<<1, 1024, 0, stream>>>(bc_src, bc_dst, bbase_src, bbase_dst, row_ptr);
  scatter_k<<<NBLK_PART, 256, 0, stream>>>((const int4*)src, (const int4*)dst,
                                           bbase_src, bbase_dst, cur_src, cur_dst,
                                           sortedS, sortedE);
  bucket_csr_k<<<NB_USED, 256, 0, stream>>>(sortedS, sortedE, bbase_src, bbase_dst,
                                            deg_out, deg_in, row_ptr, csr_src);

  // layer 1: A = (x @ W1) * deg_out^-1/2 ; B = relu(agg(A) * deg_in^-1/2 + b1)
  gemm_scale_k<IN_DIM><<<(N_NODES + 3) / 4, 256, 0, stream>>>(x, W1, deg_out, A);
  aggregate_k<<<(N_NODES + 3) / 4, 256, 0, stream>>>(A, row_ptr, csr_src, deg_in, b1, B);

  // layer 2: A = (B @ W2) * deg_out^-1/2 ; B = relu(agg(A) * deg_in^-1/2 + b2)
  gemm_scale_k<HIDDEN><<<(N_NODES + 3) / 4, 256, 0, stream>>>(B, W2, deg_out, A);
  aggregate_k<<<(N_NODES + 3) / 4, 256, 0, stream>>>(A, row_ptr, csr_src, deg_in, b2, B);

  // pool + heads
  pool_k<<<((N_NODES + 255) / 256 + 3) / 4, 256, 0, stream>>>(B, node_graph, sums, cnts);
  final_k<<<1, 256, 0, stream>>>(sums, cnts, Wmu, bmu, Wlv, blv, out);
}

// Round 3
// 517.183 us; speedup vs baseline: 2.1880x; 1.1768x over previous
//
#include <hip/hip_runtime.h>

#define N_NODES 100000
#define N_EDGES 3200000
#define N_GRAPHS 64
#define IN_DIM 128
#define HIDDEN 64
#define LATENT 16

#define NBUCK 1024
#define BSHIFT 7
#define NODES_PER_BUCK 128
#define NBLK_PART 256
#define NB_USED ((N_NODES + NODES_PER_BUCK - 1) / NODES_PER_BUCK)  // 782

// ---------------- pass A: 1024-bucket histograms of src and dst (LDS-privatized) ----
__global__ __launch_bounds__(256) void bucket_hist_k(const int4* __restrict__ src4,
                                                     const int4* __restrict__ dst4,
                                                     int* __restrict__ bc_src,
                                                     int* __restrict__ bc_dst) {
  __shared__ int hs[NBUCK], hd[NBUCK];
  int t = threadIdx.x;
  for (int i = t; i < NBUCK; i += 256) { hs[i] = 0; hd[i] = 0; }
  __syncthreads();
  const int Q = N_EDGES / 4;          // 800000
  const int QPB = Q / NBLK_PART;      // 3125
  int q0 = blockIdx.x * QPB, q1 = q0 + QPB;
  for (int i = q0 + t; i < q1; i += 256) {
    int4 s = src4[i], d = dst4[i];
    atomicAdd(&hs[s.x >> BSHIFT], 1); atomicAdd(&hs[s.y >> BSHIFT], 1);
    atomicAdd(&hs[s.z >> BSHIFT], 1); atomicAdd(&hs[s.w >> BSHIFT], 1);
    atomicAdd(&hd[d.x >> BSHIFT], 1); atomicAdd(&hd[d.y >> BSHIFT], 1);
    atomicAdd(&hd[d.z >> BSHIFT], 1); atomicAdd(&hd[d.w >> BSHIFT], 1);
  }
  __syncthreads();
  for (int i = t; i < NBUCK; i += 256) {
    if (hs[i]) atomicAdd(&bc_src[i], hs[i]);
    if (hd[i]) atomicAdd(&bc_dst[i], hd[i]);
  }
}

// ---------------- pass B: exclusive scan of both bucket-count arrays ----------------
__global__ __launch_bounds__(1024) void bucket_scan_k(const int* __restrict__ bc_src,
                                                      const int* __restrict__ bc_dst,
                                                      int* __restrict__ bbase_src,
                                                      int* __restrict__ bbase_dst,
                                                      int* __restrict__ row_ptr) {
  __shared__ int a[NBUCK], b[NBUCK];
  int t = threadIdx.x;
  int va = bc_src[t], vb = bc_dst[t];
  a[t] = va; b[t] = vb;
  __syncthreads();
  for (int off = 1; off < NBUCK; off <<= 1) {
    int xa = 0, xb = 0;
    if (t >= off) { xa = a[t - off]; xb = b[t - off]; }
    __syncthreads();
    if (t >= off) { a[t] += xa; b[t] += xb; }
    __syncthreads();
  }
  bbase_src[t] = a[t] - va;
  bbase_dst[t] = b[t] - vb;
  if (t == NBUCK - 1) {
    bbase_src[NBUCK] = a[t];
    bbase_dst[NBUCK] = b[t];
    row_ptr[N_NODES] = N_EDGES;
  }
}

// ---------------- pass C: scatter src stream and packed (ldst,src) stream into buckets ----
__global__ __launch_bounds__(256) void scatter_k(const int4* __restrict__ src4,
                                                 const int4* __restrict__ dst4,
                                                 const int* __restrict__ bbase_src,
                                                 const int* __restrict__ bbase_dst,
                                                 int* __restrict__ cur_src,
                                                 int* __restrict__ cur_dst,
                                                 int* __restrict__ sortedS,
                                                 int* __restrict__ sortedE) {
  __shared__ int hs[NBUCK], hd[NBUCK];
  __shared__ int rs[NBUCK], rd[NBUCK];
  int t = threadIdx.x;
  for (int i = t; i < NBUCK; i += 256) { hs[i] = 0; hd[i] = 0; }
  __syncthreads();
  const int Q = N_EDGES / 4;
  const int QPB = Q / NBLK_PART;
  int q0 = blockIdx.x * QPB, q1 = q0 + QPB;
  for (int i = q0 + t; i < q1; i += 256) {
    int4 s = src4[i], d = dst4[i];
    atomicAdd(&hs[s.x >> BSHIFT], 1); atomicAdd(&hs[s.y >> BSHIFT], 1);
    atomicAdd(&hs[s.z >> BSHIFT], 1); atomicAdd(&hs[s.w >> BSHIFT], 1);
    atomicAdd(&hd[d.x >> BSHIFT], 1); atomicAdd(&hd[d.y >> BSHIFT], 1);
    atomicAdd(&hd[d.z >> BSHIFT], 1); atomicAdd(&hd[d.w >> BSHIFT], 1);
  }
  __syncthreads();
  for (int i = t; i < NBUCK; i += 256) {
    rs[i] = hs[i] ? (atomicAdd(&cur_src[i], hs[i]) + bbase_src[i]) : 0;
    rd[i] = hd[i] ? (atomicAdd(&cur_dst[i], hd[i]) + bbase_dst[i]) : 0;
  }
  __syncthreads();
  for (int i = q0 + t; i < q1; i += 256) {
    int4 s = src4[i], d = dst4[i];
    int sv[4] = {s.x, s.y, s.z, s.w};
    int dv[4] = {d.x, d.y, d.z, d.w};
#pragma unroll
    for (int k = 0; k < 4; k++) {
      int ps = atomicAdd(&rs[sv[k] >> BSHIFT], 1);
      sortedS[ps] = sv[k];
      int pd = atomicAdd(&rd[dv[k] >> BSHIFT], 1);
      sortedE[pd] = ((dv[k] & (NODES_PER_BUCK - 1)) << 17) | sv[k];
    }
  }
}

// ---------------- pass D: per-bucket CSR + degrees (all atomics in LDS) ----------------
__global__ __launch_bounds__(256) void bucket_csr_k(const int* __restrict__ sortedS,
                                                    const int* __restrict__ sortedE,
                                                    const int* __restrict__ bbase_src,
                                                    const int* __restrict__ bbase_dst,
                                                    int* __restrict__ deg_out,
                                                    int* __restrict__ deg_in,
                                                    int* __restrict__ row_ptr,
                                                    int* __restrict__ csr_src) {
  __shared__ int hin[NODES_PER_BUCK], hout[NODES_PER_BUCK];
  __shared__ int scn[NODES_PER_BUCK], cur[NODES_PER_BUCK];
  int bk = blockIdx.x, t = threadIdx.x;
  int node0 = bk << BSHIFT;
  if (t < NODES_PER_BUCK) { hin[t] = 0; hout[t] = 0; cur[t] = 0; }
  __syncthreads();
  int s0 = bbase_src[bk], s1 = bbase_src[bk + 1];
  for (int j = s0 + t; j < s1; j += 256)
    atomicAdd(&hout[sortedS[j] & (NODES_PER_BUCK - 1)], 1);
  int e0 = bbase_dst[bk], e1 = bbase_dst[bk + 1];
  for (int j = e0 + t; j < e1; j += 256)
    atomicAdd(&hin[sortedE[j] >> 17], 1);
  __syncthreads();
  if (t < NODES_PER_BUCK) scn[t] = hin[t];
  __syncthreads();
  for (int off = 1; off < NODES_PER_BUCK; off <<= 1) {
    int v = 0;
    if (t < NODES_PER_BUCK && t >= off) v = scn[t - off];
    __syncthreads();
    if (t < NODES_PER_BUCK && t >= off) scn[t] += v;
    __syncthreads();
  }
  int n = node0 + t;
  if (t < NODES_PER_BUCK && n < N_NODES) {
    deg_out[n] = hout[t];
    deg_in[n] = hin[t];
    row_ptr[n] = e0 + scn[t] - hin[t];
  }
  __syncthreads();
  for (int j = e0 + t; j < e1; j += 256) {
    int v = sortedE[j];
    int ln = v >> 17;
    int pos = e0 + scn[ln] - hin[ln] + atomicAdd(&cur[ln], 1);
    csr_src[pos] = v & 0x1FFFF;
  }
}

// ---------------- register-tiled GEMM: out[n][c] = (X@W)[n][c] * rsqrt(max(deg,1)) ----
// 64x64 block tile, 4x4 per-thread tile. VALU-bound by design:
// per 4 k-steps: 4 b128 a-reads (16-lane broadcast, pad +4 kills bank alias)
// + 4 b128 b-reads (2-way, free) per 64 FMAs.
template <int IN>
__global__ __launch_bounds__(256) void gemm_tile_k(const float* __restrict__ X,
                                                   const float* __restrict__ W,
                                                   const int* __restrict__ deg,
                                                   float* __restrict__ out) {
  __shared__ float xs[64][IN + 4];
  __shared__ float ws[IN][HIDDEN];
  int t = threadIdx.x;
  int row0_blk = blockIdx.x * 64;

  // stage W (contiguous float4)
  for (int i = t; i < IN * HIDDEN / 4; i += 256)
    ((float4*)ws)[i] = ((const float4*)W)[i];
  // stage X rows (guarded), padded stride
  for (int i = t; i < 64 * (IN / 4); i += 256) {
    int r = i / (IN / 4), c4 = i % (IN / 4);
    int row = row0_blk + r;
    float4 v = make_float4(0.f, 0.f, 0.f, 0.f);
    if (row < N_NODES) v = *(const float4*)&X[(size_t)row * IN + c4 * 4];
    *(float4*)&xs[r][c4 * 4] = v;
  }
  __syncthreads();

  int w = t >> 6, lane = t & 63;
  int rg = lane >> 4, cg = lane & 15;
  int r0 = w * 16 + rg * 4;   // block-local row of my 4-row group
  int c0 = cg * 4;            // col of my 4-col group

  float acc[4][4];
#pragma unroll
  for (int i = 0; i < 4; i++)
#pragma unroll
    for (int j = 0; j < 4; j++) acc[i][j] = 0.f;

#pragma unroll 4
  for (int d4 = 0; d4 < IN / 4; d4++) {
    float4 a0 = *(const float4*)&xs[r0 + 0][d4 * 4];
    float4 a1 = *(const float4*)&xs[r0 + 1][d4 * 4];
    float4 a2 = *(const float4*)&xs[r0 + 2][d4 * 4];
    float4 a3 = *(const float4*)&xs[r0 + 3][d4 * 4];
#pragma unroll
    for (int dd = 0; dd < 4; dd++) {
      float4 b = *(const float4*)&ws[d4 * 4 + dd][c0];
      float av0 = (&a0.x)[dd], av1 = (&a1.x)[dd], av2 = (&a2.x)[dd], av3 = (&a3.x)[dd];
      acc[0][0] += av0 * b.x; acc[0][1] += av0 * b.y; acc[0][2] += av0 * b.z; acc[0][3] += av0 * b.w;
      acc[1][0] += av1 * b.x; acc[1][1] += av1 * b.y; acc[1][2] += av1 * b.z; acc[1][3] += av1 * b.w;
      acc[2][0] += av2 * b.x; acc[2][1] += av2 * b.y; acc[2][2] += av2 * b.z; acc[2][3] += av2 * b.w;
      acc[3][0] += av3 * b.x; acc[3][1] += av3 * b.y; acc[3][2] += av3 * b.z; acc[3][3] += av3 * b.w;
    }
  }

#pragma unroll
  for (int i = 0; i < 4; i++) {
    int row = row0_blk + r0 + i;
    if (row >= N_NODES) continue;
    float dg = (float)deg[row];
    if (dg < 1.f) dg = 1.f;
    float sc = rsqrtf(dg);
    float4 o = make_float4(acc[i][0] * sc, acc[i][1] * sc, acc[i][2] * sc, acc[i][3] * sc);
    *(float4*)&out[(size_t)row * HIDDEN + c0] = o;
  }
}

// ---------------- aggregate: out[n][c] = relu(rsqrt(deg_in) * sum_{e->n} hw[src_e][c] + b[c]) ----
__global__ __launch_bounds__(256) void aggregate_k(const float* __restrict__ hw,
                                                   const int* __restrict__ row_ptr,
                                                   const int* __restrict__ csr_src,
                                                   const int* __restrict__ deg_in,
                                                   const float* __restrict__ bias,
                                                   float* __restrict__ out) {
  int wave = (int)((blockIdx.x * blockDim.x + threadIdx.x) >> 6);
  int lane = threadIdx.x & 63;
  if (wave >= N_NODES) return;
  int start = row_ptr[wave], end = row_ptr[wave + 1];
  float acc = 0.f;
  int j = start;
  for (; j + 3 < end; j += 4) {
    int s0 = csr_src[j], s1 = csr_src[j + 1], s2 = csr_src[j + 2], s3 = csr_src[j + 3];
    float a0 = hw[(size_t)s0 * HIDDEN + lane];
    float a1 = hw[(size_t)s1 * HIDDEN + lane];
    float a2 = hw[(size_t)s2 * HIDDEN + lane];
    float a3 = hw[(size_t)s3 * HIDDEN + lane];
    acc += (a0 + a1) + (a2 + a3);
  }
  for (; j < end; j++) {
    int s = csr_src[j];
    acc += hw[(size_t)s * HIDDEN + lane];
  }
  float dg = (float)deg_in[wave];
  if (dg < 1.f) dg = 1.f;
  float v = acc * rsqrtf(dg) + bias[lane];
  out[(size_t)wave * HIDDEN + lane] = v > 0.f ? v : 0.f;
}

// ---------------- per-graph mean pool stage 1 (sorted node_graph, run-accumulate) ----------------
__global__ __launch_bounds__(256) void pool_k(const float* __restrict__ h,
                                              const int* __restrict__ node_graph,
                                              float* __restrict__ sums,
                                              float* __restrict__ counts) {
  const int NPW = 256;  // nodes per wave
  int wave = (int)((blockIdx.x * blockDim.x + threadIdx.x) >> 6);
  int lane = threadIdx.x & 63;
  int start = wave * NPW;
  if (start >= N_NODES) return;
  int end = start + NPW; if (end > N_NODES) end = N_NODES;
  int cur = node_graph[start];
  float acc = 0.f, cnt = 0.f;
  for (int n = start; n < end; n++) {
    int g = node_graph[n];
    if (g != cur) {
      atomicAdd(&sums[cur * HIDDEN + lane], acc);
      if (lane == 0) atomicAdd(&counts[cur], cnt);
      cur = g; acc = 0.f; cnt = 0.f;
    }
    acc += h[(size_t)n * HIDDEN + lane];
    cnt += 1.f;
  }
  atomicAdd(&sums[cur * HIDDEN + lane], acc);
  if (lane == 0) atomicAdd(&counts[cur], cnt);
}

// ---------------- final: h_graph = sums/counts; mu/logvar = h_graph @ Wmu/Wlv + b ----------------
__global__ __launch_bounds__(256) void final_k(const float* __restrict__ sums,
                                               const float* __restrict__ counts,
                                               const float* __restrict__ Wmu,
                                               const float* __restrict__ bmu,
                                               const float* __restrict__ Wlv,
                                               const float* __restrict__ blv,
                                               float* __restrict__ out) {
  __shared__ float hg[N_GRAPHS][HIDDEN];
  __shared__ float wmu[HIDDEN][LATENT];
  __shared__ float wlv[HIDDEN][LATENT];
  int t = threadIdx.x;
  for (int i = t; i < N_GRAPHS * HIDDEN; i += 256) {
    int g = i / HIDDEN;
    float c = counts[g];
    if (c < 1.f) c = 1.f;
    hg[g][i % HIDDEN] = sums[i] / c;
  }
  for (int i = t; i < HIDDEN * LATENT; i += 256) {
    wmu[i / LATENT][i % LATENT] = Wmu[i];
    wlv[i / LATENT][i % LATENT] = Wlv[i];
  }
  __syncthreads();
  for (int i = t; i < N_GRAPHS * LATENT; i += 256) {
    int g = i / LATENT, j = i % LATENT;
    float mu = bmu[j], lv = blv[j];
#pragma unroll
    for (int k = 0; k < HIDDEN; k++) {
      float v = hg[g][k];
      mu += v * wmu[k][j];
      lv += v * wlv[k][j];
    }
    out[i] = mu;
    out[N_GRAPHS * LATENT + i] = lv;
  }
}

extern "C" void kernel_launch(void* const* d_in, const int* in_sizes, int n_in,
                              void* d_out, int out_size, void* d_ws, size_t ws_size,
                              hipStream_t stream) {
  const float* x = (const float*)d_in[0];
  // d_in[1] = edge_feat: provably unused for (mu, logvar)
  const int* src = (const int*)d_in[2];
  const int* dst = (const int*)d_in[3];
  const int* node_graph = (const int*)d_in[4];
  const float* W1 = (const float*)d_in[5];
  const float* b1 = (const float*)d_in[6];
  const float* W2 = (const float*)d_in[7];
  const float* b2 = (const float*)d_in[8];
  // d_in[9] = We, d_in[10] = be: unused
  const float* Wmu = (const float*)d_in[11];
  const float* bmu = (const float*)d_in[12];
  const float* Wlv = (const float*)d_in[13];
  const float* blv = (const float*)d_in[14];
  float* out = (float*)d_out;

  char* ws = (char*)d_ws;
  // zeroed control block [0, 33280)
  int* bc_src   = (int*)(ws + 0);        // 4096
  int* bc_dst   = (int*)(ws + 4096);     // 4096
  int* cur_src  = (int*)(ws + 8192);     // 4096
  int* cur_dst  = (int*)(ws + 12288);    // 4096
  float* cnts   = (float*)(ws + 16384);  // 256 (pad 512)
  float* sums   = (float*)(ws + 16896);  // 16384
  // non-zeroed control
  int* bbase_src = (int*)(ws + 33280);   // 4100
  int* bbase_dst = (int*)(ws + 37632);   // 4100
  // big arrays
  int* deg_out = (int*)(ws + 65536);     // 400000 (pad 400128)
  int* deg_in  = (int*)(ws + 465664);    // 400000
  int* row_ptr = (int*)(ws + 865792);    // 400004
  int* csr_src = (int*)(ws + 1266176);   // 12800000
  int* sortedS = (int*)(ws + 14066176);  // 12800000 } dead after bucket_csr_k,
  int* sortedE = (int*)(ws + 26866176);  // 12800000 } region reused as A
  float* A     = (float*)(ws + 14066176);// 25600000 (alias of sortedS+sortedE)
  float* B     = (float*)(ws + 39666176);// 25600000 → end 65266176

  hipMemsetAsync(ws, 0, 33280, stream);

  bucket_hist_k<<<NBLK_PART, 256, 0, stream>>>((const int4*)src, (const int4*)dst,
                                               bc_src, bc_dst);
  bucket_scan_k<<<1, 1024, 0, stream>>>(bc_src, bc_dst, bbase_src, bbase_dst, row_ptr);
  scatter_k<<<NBLK_PART, 256, 0, stream>>>((const int4*)src, (const int4*)dst,
                                           bbase_src, bbase_dst, cur_src, cur_dst,
                                           sortedS, sortedE);
  bucket_csr_k<<<NB_USED, 256, 0, stream>>>(sortedS, sortedE, bbase_src, bbase_dst,
                                            deg_out, deg_in, row_ptr, csr_src);

  const int GEMM_BLKS = (N_NODES + 63) / 64;  // 1563

  // layer 1: A = (x @ W1) * deg_out^-1/2 ; B = relu(agg(A) * deg_in^-1/2 + b1)
  gemm_tile_k<IN_DIM><<<GEMM_BLKS, 256, 0, stream>>>(x, W1, deg_out, A);
  aggregate_k<<<(N_NODES + 3) / 4, 256, 0, stream>>>(A, row_ptr, csr_src, deg_in, b1, B);

  // layer 2: A = (B @ W2) * deg_out^-1/2 ; B = relu(agg(A) * deg_in^-1/2 + b2)
  gemm_tile_k<HIDDEN><<<GEMM_BLKS, 256, 0, stream>>>(B, W2, deg_out, A);
  aggregate_k<<<(N_NODES + 3) / 4, 256, 0, stream>>>(A, row_ptr, csr_src, deg_in, b2, B);

  // pool + heads
  pool_k<<<((N_NODES + 255) / 256 + 3) / 4, 256, 0, stream>>>(B, node_graph, sums, cnts);
  final_k<<<1, 256, 0, stream>>>(sums, cnts, Wmu, bmu, Wlv, blv, out);
}

// Round 4
// 454.792 us; speedup vs baseline: 2.4881x; 1.1372x over previous
//
#include <hip/hip_runtime.h>
#include <hip/hip_fp16.h>

#define N_NODES 100000
#define N_EDGES 3200000
#define N_GRAPHS 64
#define IN_DIM 128
#define HIDDEN 64
#define LATENT 16

#define NBUCK 1024
#define BSHIFT 7
#define NODES_PER_BUCK 128
#define NBLK_PART 256
#define NB_USED ((N_NODES + NODES_PER_BUCK - 1) / NODES_PER_BUCK)  // 782

// ---------------- tiny zero kernel (hipMemsetAsync's fill kernel cost 121us!) ----
__global__ __launch_bounds__(256) void zero_k(int4* __restrict__ p, int n4) {
  int i = blockIdx.x * 256 + threadIdx.x;
  if (i < n4) p[i] = make_int4(0, 0, 0, 0);
}

// ---------------- pass A: 1024-bucket histograms of src and dst (LDS-privatized) ----
__global__ __launch_bounds__(256) void bucket_hist_k(const int4* __restrict__ src4,
                                                     const int4* __restrict__ dst4,
                                                     int* __restrict__ bc_src,
                                                     int* __restrict__ bc_dst) {
  __shared__ int hs[NBUCK], hd[NBUCK];
  int t = threadIdx.x;
  for (int i = t; i < NBUCK; i += 256) { hs[i] = 0; hd[i] = 0; }
  __syncthreads();
  const int Q = N_EDGES / 4;          // 800000
  const int QPB = Q / NBLK_PART;      // 3125
  int q0 = blockIdx.x * QPB, q1 = q0 + QPB;
  for (int i = q0 + t; i < q1; i += 256) {
    int4 s = src4[i], d = dst4[i];
    atomicAdd(&hs[s.x >> BSHIFT], 1); atomicAdd(&hs[s.y >> BSHIFT], 1);
    atomicAdd(&hs[s.z >> BSHIFT], 1); atomicAdd(&hs[s.w >> BSHIFT], 1);
    atomicAdd(&hd[d.x >> BSHIFT], 1); atomicAdd(&hd[d.y >> BSHIFT], 1);
    atomicAdd(&hd[d.z >> BSHIFT], 1); atomicAdd(&hd[d.w >> BSHIFT], 1);
  }
  __syncthreads();
  for (int i = t; i < NBUCK; i += 256) {
    if (hs[i]) atomicAdd(&bc_src[i], hs[i]);
    if (hd[i]) atomicAdd(&bc_dst[i], hd[i]);
  }
}

// ---------------- pass B: exclusive scan of both bucket-count arrays ----------------
__global__ __launch_bounds__(1024) void bucket_scan_k(const int* __restrict__ bc_src,
                                                      const int* __restrict__ bc_dst,
                                                      int* __restrict__ bbase_src,
                                                      int* __restrict__ bbase_dst,
                                                      int* __restrict__ row_ptr) {
  __shared__ int a[NBUCK], b[NBUCK];
  int t = threadIdx.x;
  int va = bc_src[t], vb = bc_dst[t];
  a[t] = va; b[t] = vb;
  __syncthreads();
  for (int off = 1; off < NBUCK; off <<= 1) {
    int xa = 0, xb = 0;
    if (t >= off) { xa = a[t - off]; xb = b[t - off]; }
    __syncthreads();
    if (t >= off) { a[t] += xa; b[t] += xb; }
    __syncthreads();
  }
  bbase_src[t] = a[t] - va;
  bbase_dst[t] = b[t] - vb;
  if (t == NBUCK - 1) {
    bbase_src[NBUCK] = a[t];
    bbase_dst[NBUCK] = b[t];
    row_ptr[N_NODES] = N_EDGES;
  }
}

// ---------------- pass C: scatter src stream and packed (ldst,src) stream into buckets ----
__global__ __launch_bounds__(256) void scatter_k(const int4* __restrict__ src4,
                                                 const int4* __restrict__ dst4,
                                                 const int* __restrict__ bbase_src,
                                                 const int* __restrict__ bbase_dst,
                                                 int* __restrict__ cur_src,
                                                 int* __restrict__ cur_dst,
                                                 int* __restrict__ sortedS,
                                                 int* __restrict__ sortedE) {
  __shared__ int hs[NBUCK], hd[NBUCK];
  __shared__ int rs[NBUCK], rd[NBUCK];
  int t = threadIdx.x;
  for (int i = t; i < NBUCK; i += 256) { hs[i] = 0; hd[i] = 0; }
  __syncthreads();
  const int Q = N_EDGES / 4;
  const int QPB = Q / NBLK_PART;
  int q0 = blockIdx.x * QPB, q1 = q0 + QPB;
  for (int i = q0 + t; i < q1; i += 256) {
    int4 s = src4[i], d = dst4[i];
    atomicAdd(&hs[s.x >> BSHIFT], 1); atomicAdd(&hs[s.y >> BSHIFT], 1);
    atomicAdd(&hs[s.z >> BSHIFT], 1); atomicAdd(&hs[s.w >> BSHIFT], 1);
    atomicAdd(&hd[d.x >> BSHIFT], 1); atomicAdd(&hd[d.y >> BSHIFT], 1);
    atomicAdd(&hd[d.z >> BSHIFT], 1); atomicAdd(&hd[d.w >> BSHIFT], 1);
  }
  __syncthreads();
  for (int i = t; i < NBUCK; i += 256) {
    rs[i] = hs[i] ? (atomicAdd(&cur_src[i], hs[i]) + bbase_src[i]) : 0;
    rd[i] = hd[i] ? (atomicAdd(&cur_dst[i], hd[i]) + bbase_dst[i]) : 0;
  }
  __syncthreads();
  for (int i = q0 + t; i < q1; i += 256) {
    int4 s = src4[i], d = dst4[i];
    int sv[4] = {s.x, s.y, s.z, s.w};
    int dv[4] = {d.x, d.y, d.z, d.w};
#pragma unroll
    for (int k = 0; k < 4; k++) {
      int ps = atomicAdd(&rs[sv[k] >> BSHIFT], 1);
      sortedS[ps] = sv[k];
      int pd = atomicAdd(&rd[dv[k] >> BSHIFT], 1);
      sortedE[pd] = ((dv[k] & (NODES_PER_BUCK - 1)) << 17) | sv[k];
    }
  }
}

// ---------------- pass D: per-bucket CSR + degrees (all atomics in LDS) ----------------
__global__ __launch_bounds__(256) void bucket_csr_k(const int* __restrict__ sortedS,
                                                    const int* __restrict__ sortedE,
                                                    const int* __restrict__ bbase_src,
                                                    const int* __restrict__ bbase_dst,
                                                    int* __restrict__ deg_out,
                                                    int* __restrict__ deg_in,
                                                    int* __restrict__ row_ptr,
                                                    int* __restrict__ csr_src) {
  __shared__ int hin[NODES_PER_BUCK], hout[NODES_PER_BUCK];
  __shared__ int scn[NODES_PER_BUCK], cur[NODES_PER_BUCK];
  int bk = blockIdx.x, t = threadIdx.x;
  int node0 = bk << BSHIFT;
  if (t < NODES_PER_BUCK) { hin[t] = 0; hout[t] = 0; cur[t] = 0; }
  __syncthreads();
  int s0 = bbase_src[bk], s1 = bbase_src[bk + 1];
  for (int j = s0 + t; j < s1; j += 256)
    atomicAdd(&hout[sortedS[j] & (NODES_PER_BUCK - 1)], 1);
  int e0 = bbase_dst[bk], e1 = bbase_dst[bk + 1];
  for (int j = e0 + t; j < e1; j += 256)
    atomicAdd(&hin[sortedE[j] >> 17], 1);
  __syncthreads();
  if (t < NODES_PER_BUCK) scn[t] = hin[t];
  __syncthreads();
  for (int off = 1; off < NODES_PER_BUCK; off <<= 1) {
    int v = 0;
    if (t < NODES_PER_BUCK && t >= off) v = scn[t - off];
    __syncthreads();
    if (t < NODES_PER_BUCK && t >= off) scn[t] += v;
    __syncthreads();
  }
  int n = node0 + t;
  if (t < NODES_PER_BUCK && n < N_NODES) {
    deg_out[n] = hout[t];
    deg_in[n] = hin[t];
    row_ptr[n] = e0 + scn[t] - hin[t];
  }
  __syncthreads();
  for (int j = e0 + t; j < e1; j += 256) {
    int v = sortedE[j];
    int ln = v >> 17;
    int pos = e0 + scn[ln] - hin[ln] + atomicAdd(&cur[ln], 1);
    csr_src[pos] = v & 0x1FFFF;
  }
}

// ---------------- register-tiled GEMM: out[n][c] = (X@W)[n][c] * rsqrt(max(deg,1)) ----
// 64x64 block tile, 4x4 per-thread tile. OT=__half packs the result for the gather.
template <int IN, typename OT>
__global__ __launch_bounds__(256) void gemm_tile_k(const float* __restrict__ X,
                                                   const float* __restrict__ W,
                                                   const int* __restrict__ deg,
                                                   OT* __restrict__ out) {
  __shared__ float xs[64][IN + 4];
  __shared__ float ws[IN][HIDDEN];
  int t = threadIdx.x;
  int row0_blk = blockIdx.x * 64;

  for (int i = t; i < IN * HIDDEN / 4; i += 256)
    ((float4*)ws)[i] = ((const float4*)W)[i];
  for (int i = t; i < 64 * (IN / 4); i += 256) {
    int r = i / (IN / 4), c4 = i % (IN / 4);
    int row = row0_blk + r;
    float4 v = make_float4(0.f, 0.f, 0.f, 0.f);
    if (row < N_NODES) v = *(const float4*)&X[(size_t)row * IN + c4 * 4];
    *(float4*)&xs[r][c4 * 4] = v;
  }
  __syncthreads();

  int w = t >> 6, lane = t & 63;
  int rg = lane >> 4, cg = lane & 15;
  int r0 = w * 16 + rg * 4;
  int c0 = cg * 4;

  float acc[4][4];
#pragma unroll
  for (int i = 0; i < 4; i++)
#pragma unroll
    for (int j = 0; j < 4; j++) acc[i][j] = 0.f;

#pragma unroll 4
  for (int d4 = 0; d4 < IN / 4; d4++) {
    float4 a0 = *(const float4*)&xs[r0 + 0][d4 * 4];
    float4 a1 = *(const float4*)&xs[r0 + 1][d4 * 4];
    float4 a2 = *(const float4*)&xs[r0 + 2][d4 * 4];
    float4 a3 = *(const float4*)&xs[r0 + 3][d4 * 4];
#pragma unroll
    for (int dd = 0; dd < 4; dd++) {
      float4 b = *(const float4*)&ws[d4 * 4 + dd][c0];
      float av0 = (&a0.x)[dd], av1 = (&a1.x)[dd], av2 = (&a2.x)[dd], av3 = (&a3.x)[dd];
      acc[0][0] += av0 * b.x; acc[0][1] += av0 * b.y; acc[0][2] += av0 * b.z; acc[0][3] += av0 * b.w;
      acc[1][0] += av1 * b.x; acc[1][1] += av1 * b.y; acc[1][2] += av1 * b.z; acc[1][3] += av1 * b.w;
      acc[2][0] += av2 * b.x; acc[2][1] += av2 * b.y; acc[2][2] += av2 * b.z; acc[2][3] += av2 * b.w;
      acc[3][0] += av3 * b.x; acc[3][1] += av3 * b.y; acc[3][2] += av3 * b.z; acc[3][3] += av3 * b.w;
    }
  }

#pragma unroll
  for (int i = 0; i < 4; i++) {
    int row = row0_blk + r0 + i;
    if (row >= N_NODES) continue;
    float dg = (float)deg[row];
    if (dg < 1.f) dg = 1.f;
    float sc = rsqrtf(dg);
    if constexpr (sizeof(OT) == 2) {
      __half2 p0 = __floats2half2_rn(acc[i][0] * sc, acc[i][1] * sc);
      __half2 p1 = __floats2half2_rn(acc[i][2] * sc, acc[i][3] * sc);
      union { __half2 h2[2]; float2 f2; } u;
      u.h2[0] = p0; u.h2[1] = p1;
      *(float2*)&out[(size_t)row * HIDDEN + c0] = u.f2;
    } else {
      float4 o = make_float4(acc[i][0] * sc, acc[i][1] * sc, acc[i][2] * sc, acc[i][3] * sc);
      *(float4*)&out[(size_t)row * HIDDEN + c0] = o;
    }
  }
}

// ---------------- aggregate (fp16 gather): out[n][c] = relu(rsqrt(deg_in)*sum hw[src][c] + b[c]) ----
__global__ __launch_bounds__(256) void aggregate_k(const __half* __restrict__ hw,
                                                   const int* __restrict__ row_ptr,
                                                   const int* __restrict__ csr_src,
                                                   const int* __restrict__ deg_in,
                                                   const float* __restrict__ bias,
                                                   float* __restrict__ out) {
  int wave = (int)((blockIdx.x * blockDim.x + threadIdx.x) >> 6);
  int lane = threadIdx.x & 63;
  if (wave >= N_NODES) return;
  int start = row_ptr[wave], end = row_ptr[wave + 1];
  float acc = 0.f;
  int j = start;
  for (; j + 7 < end; j += 8) {
    int s0 = csr_src[j + 0], s1 = csr_src[j + 1], s2 = csr_src[j + 2], s3 = csr_src[j + 3];
    int s4 = csr_src[j + 4], s5 = csr_src[j + 5], s6 = csr_src[j + 6], s7 = csr_src[j + 7];
    float a0 = __half2float(hw[(size_t)s0 * HIDDEN + lane]);
    float a1 = __half2float(hw[(size_t)s1 * HIDDEN + lane]);
    float a2 = __half2float(hw[(size_t)s2 * HIDDEN + lane]);
    float a3 = __half2float(hw[(size_t)s3 * HIDDEN + lane]);
    float a4 = __half2float(hw[(size_t)s4 * HIDDEN + lane]);
    float a5 = __half2float(hw[(size_t)s5 * HIDDEN + lane]);
    float a6 = __half2float(hw[(size_t)s6 * HIDDEN + lane]);
    float a7 = __half2float(hw[(size_t)s7 * HIDDEN + lane]);
    acc += ((a0 + a1) + (a2 + a3)) + ((a4 + a5) + (a6 + a7));
  }
  for (; j < end; j++) {
    int s = csr_src[j];
    acc += __half2float(hw[(size_t)s * HIDDEN + lane]);
  }
  float dg = (float)deg_in[wave];
  if (dg < 1.f) dg = 1.f;
  float v = acc * rsqrtf(dg) + bias[lane];
  out[(size_t)wave * HIDDEN + lane] = v > 0.f ? v : 0.f;
}

// ---------------- per-graph mean pool stage 1 (sorted node_graph, run-accumulate) ----------------
__global__ __launch_bounds__(256) void pool_k(const float* __restrict__ h,
                                              const int* __restrict__ node_graph,
                                              float* __restrict__ sums,
                                              float* __restrict__ counts) {
  const int NPW = 256;  // nodes per wave
  int wave = (int)((blockIdx.x * blockDim.x + threadIdx.x) >> 6);
  int lane = threadIdx.x & 63;
  int start = wave * NPW;
  if (start >= N_NODES) return;
  int end = start + NPW; if (end > N_NODES) end = N_NODES;
  int cur = node_graph[start];
  float acc = 0.f, cnt = 0.f;
  for (int n = start; n < end; n++) {
    int g = node_graph[n];
    if (g != cur) {
      atomicAdd(&sums[cur * HIDDEN + lane], acc);
      if (lane == 0) atomicAdd(&counts[cur], cnt);
      cur = g; acc = 0.f; cnt = 0.f;
    }
    acc += h[(size_t)n * HIDDEN + lane];
    cnt += 1.f;
  }
  atomicAdd(&sums[cur * HIDDEN + lane], acc);
  if (lane == 0) atomicAdd(&counts[cur], cnt);
}

// ---------------- final: h_graph = sums/counts; mu/logvar = h_graph @ Wmu/Wlv + b ----------------
__global__ __launch_bounds__(256) void final_k(const float* __restrict__ sums,
                                               const float* __restrict__ counts,
                                               const float* __restrict__ Wmu,
                                               const float* __restrict__ bmu,
                                               const float* __restrict__ Wlv,
                                               const float* __restrict__ blv,
                                               float* __restrict__ out) {
  __shared__ float hg[N_GRAPHS][HIDDEN];
  __shared__ float wmu[HIDDEN][LATENT];
  __shared__ float wlv[HIDDEN][LATENT];
  int t = threadIdx.x;
  for (int i = t; i < N_GRAPHS * HIDDEN; i += 256) {
    int g = i / HIDDEN;
    float c = counts[g];
    if (c < 1.f) c = 1.f;
    hg[g][i % HIDDEN] = sums[i] / c;
  }
  for (int i = t; i < HIDDEN * LATENT; i += 256) {
    wmu[i / LATENT][i % LATENT] = Wmu[i];
    wlv[i / LATENT][i % LATENT] = Wlv[i];
  }
  __syncthreads();
  for (int i = t; i < N_GRAPHS * LATENT; i += 256) {
    int g = i / LATENT, j = i % LATENT;
    float mu = bmu[j], lv = blv[j];
#pragma unroll
    for (int k = 0; k < HIDDEN; k++) {
      float v = hg[g][k];
      mu += v * wmu[k][j];
      lv += v * wlv[k][j];
    }
    out[i] = mu;
    out[N_GRAPHS * LATENT + i] = lv;
  }
}

extern "C" void kernel_launch(void* const* d_in, const int* in_sizes, int n_in,
                              void* d_out, int out_size, void* d_ws, size_t ws_size,
                              hipStream_t stream) {
  const float* x = (const float*)d_in[0];
  // d_in[1] = edge_feat: provably unused for (mu, logvar)
  const int* src = (const int*)d_in[2];
  const int* dst = (const int*)d_in[3];
  const int* node_graph = (const int*)d_in[4];
  const float* W1 = (const float*)d_in[5];
  const float* b1 = (const float*)d_in[6];
  const float* W2 = (const float*)d_in[7];
  const float* b2 = (const float*)d_in[8];
  // d_in[9] = We, d_in[10] = be: unused
  const float* Wmu = (const float*)d_in[11];
  const float* bmu = (const float*)d_in[12];
  const float* Wlv = (const float*)d_in[13];
  const float* blv = (const float*)d_in[14];
  float* out = (float*)d_out;

  char* ws = (char*)d_ws;
  // zeroed control block [0, 33280)
  int* bc_src   = (int*)(ws + 0);        // 4096
  int* bc_dst   = (int*)(ws + 4096);     // 4096
  int* cur_src  = (int*)(ws + 8192);     // 4096
  int* cur_dst  = (int*)(ws + 12288);    // 4096
  float* cnts   = (float*)(ws + 16384);  // 256 (pad 512)
  float* sums   = (float*)(ws + 16896);  // 16384
  // non-zeroed control
  int* bbase_src = (int*)(ws + 33280);   // 4100
  int* bbase_dst = (int*)(ws + 37632);   // 4100
  // big arrays
  int* deg_out = (int*)(ws + 65536);     // 400000 (pad 400128)
  int* deg_in  = (int*)(ws + 465664);    // 400000
  int* row_ptr = (int*)(ws + 865792);    // 400004
  int* csr_src = (int*)(ws + 1266176);   // 12800000
  int* sortedS = (int*)(ws + 14066176);  // 12800000 } dead after bucket_csr_k,
  int* sortedE = (int*)(ws + 26866176);  // 12800000 } region reused as A (fp16)
  __half* A    = (__half*)(ws + 14066176);// 12800000 (alias of sortedS)
  float* B     = (float*)(ws + 39666176);// 25600000 → end 65266176

  zero_k<<<(33280 / 16 + 255) / 256, 256, 0, stream>>>((int4*)ws, 33280 / 16);

  bucket_hist_k<<<NBLK_PART, 256, 0, stream>>>((const int4*)src, (const int4*)dst,
                                               bc_src, bc_dst);
  bucket_scan_k<<<1, 1024, 0, stream>>>(bc_src, bc_dst, bbase_src, bbase_dst, row_ptr);
  scatter_k<<<NBLK_PART, 256, 0, stream>>>((const int4*)src, (const int4*)dst,
                                           bbase_src, bbase_dst, cur_src, cur_dst,
                                           sortedS, sortedE);
  bucket_csr_k<<<NB_USED, 256, 0, stream>>>(sortedS, sortedE, bbase_src, bbase_dst,
                                            deg_out, deg_in, row_ptr, csr_src);

  const int GEMM_BLKS = (N_NODES + 63) / 64;  // 1563

  // layer 1: A = fp16((x @ W1) * deg_out^-1/2) ; B = relu(agg(A) * deg_in^-1/2 + b1)
  gemm_tile_k<IN_DIM, __half><<<GEMM_BLKS, 256, 0, stream>>>(x, W1, deg_out, A);
  aggregate_k<<<(N_NODES + 3) / 4, 256, 0, stream>>>(A, row_ptr, csr_src, deg_in, b1, B);

  // layer 2: A = fp16((B @ W2) * deg_out^-1/2) ; B = relu(agg(A) * deg_in^-1/2 + b2)
  gemm_tile_k<HIDDEN, __half><<<GEMM_BLKS, 256, 0, stream>>>(B, W2, deg_out, A);
  aggregate_k<<<(N_NODES + 3) / 4, 256, 0, stream>>>(A, row_ptr, csr_src, deg_in, b2, B);

  // pool + heads
  pool_k<<<((N_NODES + 255) / 256 + 3) / 4, 256, 0, stream>>>(B, node_graph, sums, cnts);
  final_k<<<1, 256, 0, stream>>>(sums, cnts, Wmu, bmu, Wlv, blv, out);
}

// Round 5
// 437.846 us; speedup vs baseline: 2.5844x; 1.0387x over previous
//
#include <hip/hip_runtime.h>
#include <hip/hip_fp16.h>

#define N_NODES 100000
#define N_EDGES 3200000
#define N_GRAPHS 64
#define IN_DIM 128
#define HIDDEN 64
#define LATENT 16

#define NBUCK 1024
#define BSHIFT 7
#define NODES_PER_BUCK 128
#define NBLK_PART 256
#define NB_USED ((N_NODES + NODES_PER_BUCK - 1) / NODES_PER_BUCK)  // 782

// ---------------- tiny zero kernel ----------------
__global__ __launch_bounds__(256) void zero_k(int4* __restrict__ p, int n4) {
  int i = blockIdx.x * 256 + threadIdx.x;
  if (i < n4) p[i] = make_int4(0, 0, 0, 0);
}

// ---------------- pass A: 1024-bucket histograms; also dump per-block counts ----
__global__ __launch_bounds__(256) void bucket_hist_k(const int4* __restrict__ src4,
                                                     const int4* __restrict__ dst4,
                                                     int* __restrict__ bc_src,
                                                     int* __restrict__ bc_dst,
                                                     int* __restrict__ tbl_src,
                                                     int* __restrict__ tbl_dst) {
  __shared__ int hs[NBUCK], hd[NBUCK];
  int t = threadIdx.x;
  for (int i = t; i < NBUCK; i += 256) { hs[i] = 0; hd[i] = 0; }
  __syncthreads();
  const int Q = N_EDGES / 4;          // 800000
  const int QPB = Q / NBLK_PART;      // 3125
  int q0 = blockIdx.x * QPB, q1 = q0 + QPB;
  for (int i = q0 + t; i < q1; i += 256) {
    int4 s = src4[i], d = dst4[i];
    atomicAdd(&hs[s.x >> BSHIFT], 1); atomicAdd(&hs[s.y >> BSHIFT], 1);
    atomicAdd(&hs[s.z >> BSHIFT], 1); atomicAdd(&hs[s.w >> BSHIFT], 1);
    atomicAdd(&hd[d.x >> BSHIFT], 1); atomicAdd(&hd[d.y >> BSHIFT], 1);
    atomicAdd(&hd[d.z >> BSHIFT], 1); atomicAdd(&hd[d.w >> BSHIFT], 1);
  }
  __syncthreads();
  for (int i = t; i < NBUCK; i += 256) {
    int a = hs[i], b = hd[i];
    tbl_src[blockIdx.x * NBUCK + i] = a;
    tbl_dst[blockIdx.x * NBUCK + i] = b;
    if (a) atomicAdd(&bc_src[i], a);
    if (b) atomicAdd(&bc_dst[i], b);
  }
}

// ---------------- pass B: exclusive scan of both bucket-count arrays ----------------
__global__ __launch_bounds__(1024) void bucket_scan_k(const int* __restrict__ bc_src,
                                                      const int* __restrict__ bc_dst,
                                                      int* __restrict__ bbase_src,
                                                      int* __restrict__ bbase_dst,
                                                      int* __restrict__ row_ptr) {
  __shared__ int a[NBUCK], b[NBUCK];
  int t = threadIdx.x;
  int va = bc_src[t], vb = bc_dst[t];
  a[t] = va; b[t] = vb;
  __syncthreads();
  for (int off = 1; off < NBUCK; off <<= 1) {
    int xa = 0, xb = 0;
    if (t >= off) { xa = a[t - off]; xb = b[t - off]; }
    __syncthreads();
    if (t >= off) { a[t] += xa; b[t] += xb; }
    __syncthreads();
  }
  bbase_src[t] = a[t] - va;
  bbase_dst[t] = b[t] - vb;
  if (t == NBUCK - 1) {
    bbase_src[NBUCK] = a[t];
    bbase_dst[NBUCK] = b[t];
    row_ptr[N_NODES] = N_EDGES;
  }
}

// ---------------- pass C: scatter using precomputed per-block counts ----------------
__global__ __launch_bounds__(256) void scatter_k(const int4* __restrict__ src4,
                                                 const int4* __restrict__ dst4,
                                                 const int* __restrict__ bbase_src,
                                                 const int* __restrict__ bbase_dst,
                                                 const int* __restrict__ tbl_src,
                                                 const int* __restrict__ tbl_dst,
                                                 int* __restrict__ cur_src,
                                                 int* __restrict__ cur_dst,
                                                 int* __restrict__ sortedS,
                                                 int* __restrict__ sortedE) {
  __shared__ int rs[NBUCK], rd[NBUCK];
  int t = threadIdx.x;
  // reserve this block's contiguous chunk per bucket (counts precomputed in hist)
  for (int i = t; i < NBUCK; i += 256) {
    int a = tbl_src[blockIdx.x * NBUCK + i];
    int b = tbl_dst[blockIdx.x * NBUCK + i];
    rs[i] = a ? (atomicAdd(&cur_src[i], a) + bbase_src[i]) : 0;
    rd[i] = b ? (atomicAdd(&cur_dst[i], b) + bbase_dst[i]) : 0;
  }
  __syncthreads();
  const int Q = N_EDGES / 4;
  const int QPB = Q / NBLK_PART;
  int q0 = blockIdx.x * QPB, q1 = q0 + QPB;
  for (int i = q0 + t; i < q1; i += 256) {
    int4 s = src4[i], d = dst4[i];
    int sv[4] = {s.x, s.y, s.z, s.w};
    int dv[4] = {d.x, d.y, d.z, d.w};
#pragma unroll
    for (int k = 0; k < 4; k++) {
      int ps = atomicAdd(&rs[sv[k] >> BSHIFT], 1);
      sortedS[ps] = sv[k];
      int pd = atomicAdd(&rd[dv[k] >> BSHIFT], 1);
      sortedE[pd] = ((dv[k] & (NODES_PER_BUCK - 1)) << 17) | sv[k];
    }
  }
}

// ---------------- pass D: per-bucket CSR + degrees (all atomics in LDS) ----------------
__global__ __launch_bounds__(256) void bucket_csr_k(const int* __restrict__ sortedS,
                                                    const int* __restrict__ sortedE,
                                                    const int* __restrict__ bbase_src,
                                                    const int* __restrict__ bbase_dst,
                                                    int* __restrict__ deg_out,
                                                    int* __restrict__ deg_in,
                                                    int* __restrict__ row_ptr,
                                                    int* __restrict__ csr_src) {
  __shared__ int hin[NODES_PER_BUCK], hout[NODES_PER_BUCK];
  __shared__ int scn[NODES_PER_BUCK], cur[NODES_PER_BUCK];
  int bk = blockIdx.x, t = threadIdx.x;
  int node0 = bk << BSHIFT;
  if (t < NODES_PER_BUCK) { hin[t] = 0; hout[t] = 0; cur[t] = 0; }
  __syncthreads();
  int s0 = bbase_src[bk], s1 = bbase_src[bk + 1];
  for (int j = s0 + t; j < s1; j += 256)
    atomicAdd(&hout[sortedS[j] & (NODES_PER_BUCK - 1)], 1);
  int e0 = bbase_dst[bk], e1 = bbase_dst[bk + 1];
  for (int j = e0 + t; j < e1; j += 256)
    atomicAdd(&hin[sortedE[j] >> 17], 1);
  __syncthreads();
  if (t < NODES_PER_BUCK) scn[t] = hin[t];
  __syncthreads();
  for (int off = 1; off < NODES_PER_BUCK; off <<= 1) {
    int v = 0;
    if (t < NODES_PER_BUCK && t >= off) v = scn[t - off];
    __syncthreads();
    if (t < NODES_PER_BUCK && t >= off) scn[t] += v;
    __syncthreads();
  }
  int n = node0 + t;
  if (t < NODES_PER_BUCK && n < N_NODES) {
    deg_out[n] = hout[t];
    deg_in[n] = hin[t];
    row_ptr[n] = e0 + scn[t] - hin[t];
  }
  __syncthreads();
  for (int j = e0 + t; j < e1; j += 256) {
    int v = sortedE[j];
    int ln = v >> 17;
    int pos = e0 + scn[ln] - hin[ln] + atomicAdd(&cur[ln], 1);
    csr_src[pos] = v & 0x1FFFF;
  }
}

// ---------------- register-tiled GEMM: out[n][c] = (X@W)[n][c] * rsqrt(max(deg,1)) ----
template <int IN, typename OT>
__global__ __launch_bounds__(256) void gemm_tile_k(const float* __restrict__ X,
                                                   const float* __restrict__ W,
                                                   const int* __restrict__ deg,
                                                   OT* __restrict__ out) {
  __shared__ float xs[64][IN + 4];
  __shared__ float ws[IN][HIDDEN];
  int t = threadIdx.x;
  int row0_blk = blockIdx.x * 64;

  for (int i = t; i < IN * HIDDEN / 4; i += 256)
    ((float4*)ws)[i] = ((const float4*)W)[i];
  for (int i = t; i < 64 * (IN / 4); i += 256) {
    int r = i / (IN / 4), c4 = i % (IN / 4);
    int row = row0_blk + r;
    float4 v = make_float4(0.f, 0.f, 0.f, 0.f);
    if (row < N_NODES) v = *(const float4*)&X[(size_t)row * IN + c4 * 4];
    *(float4*)&xs[r][c4 * 4] = v;
  }
  __syncthreads();

  int w = t >> 6, lane = t & 63;
  int rg = lane >> 4, cg = lane & 15;
  int r0 = w * 16 + rg * 4;
  int c0 = cg * 4;

  float acc[4][4];
#pragma unroll
  for (int i = 0; i < 4; i++)
#pragma unroll
    for (int j = 0; j < 4; j++) acc[i][j] = 0.f;

#pragma unroll 4
  for (int d4 = 0; d4 < IN / 4; d4++) {
    float4 a0 = *(const float4*)&xs[r0 + 0][d4 * 4];
    float4 a1 = *(const float4*)&xs[r0 + 1][d4 * 4];
    float4 a2 = *(const float4*)&xs[r0 + 2][d4 * 4];
    float4 a3 = *(const float4*)&xs[r0 + 3][d4 * 4];
#pragma unroll
    for (int dd = 0; dd < 4; dd++) {
      float4 b = *(const float4*)&ws[d4 * 4 + dd][c0];
      float av0 = (&a0.x)[dd], av1 = (&a1.x)[dd], av2 = (&a2.x)[dd], av3 = (&a3.x)[dd];
      acc[0][0] += av0 * b.x; acc[0][1] += av0 * b.y; acc[0][2] += av0 * b.z; acc[0][3] += av0 * b.w;
      acc[1][0] += av1 * b.x; acc[1][1] += av1 * b.y; acc[1][2] += av1 * b.z; acc[1][3] += av1 * b.w;
      acc[2][0] += av2 * b.x; acc[2][1] += av2 * b.y; acc[2][2] += av2 * b.z; acc[2][3] += av2 * b.w;
      acc[3][0] += av3 * b.x; acc[3][1] += av3 * b.y; acc[3][2] += av3 * b.z; acc[3][3] += av3 * b.w;
    }
  }

#pragma unroll
  for (int i = 0; i < 4; i++) {
    int row = row0_blk + r0 + i;
    if (row >= N_NODES) continue;
    float dg = (float)deg[row];
    if (dg < 1.f) dg = 1.f;
    float sc = rsqrtf(dg);
    if constexpr (sizeof(OT) == 2) {
      __half2 p0 = __floats2half2_rn(acc[i][0] * sc, acc[i][1] * sc);
      __half2 p1 = __floats2half2_rn(acc[i][2] * sc, acc[i][3] * sc);
      union { __half2 h2[2]; float2 f2; } u;
      u.h2[0] = p0; u.h2[1] = p1;
      *(float2*)&out[(size_t)row * HIDDEN + c0] = u.f2;
    } else {
      float4 o = make_float4(acc[i][0] * sc, acc[i][1] * sc, acc[i][2] * sc, acc[i][3] * sc);
      *(float4*)&out[(size_t)row * HIDDEN + c0] = o;
    }
  }
}

// ---------------- aggregate (fp16 gather, unroll 16): relu(rsqrt(deg)*sum + b) ----
__global__ __launch_bounds__(256) void aggregate_k(const __half* __restrict__ hw,
                                                   const int* __restrict__ row_ptr,
                                                   const int* __restrict__ csr_src,
                                                   const int* __restrict__ deg_in,
                                                   const float* __restrict__ bias,
                                                   float* __restrict__ out) {
  int wave = (int)((blockIdx.x * blockDim.x + threadIdx.x) >> 6);
  int lane = threadIdx.x & 63;
  if (wave >= N_NODES) return;
  int start = row_ptr[wave], end = row_ptr[wave + 1];
  float acc = 0.f;
  int j = start;
  for (; j + 15 < end; j += 16) {
    int idx[16];
#pragma unroll
    for (int k = 0; k < 16; k++) idx[k] = csr_src[j + k];
    float a[16];
#pragma unroll
    for (int k = 0; k < 16; k++) a[k] = __half2float(hw[(size_t)idx[k] * HIDDEN + lane]);
    float s01 = (a[0] + a[1]) + (a[2] + a[3]);
    float s23 = (a[4] + a[5]) + (a[6] + a[7]);
    float s45 = (a[8] + a[9]) + (a[10] + a[11]);
    float s67 = (a[12] + a[13]) + (a[14] + a[15]);
    acc += (s01 + s23) + (s45 + s67);
  }
  for (; j + 7 < end; j += 8) {
    int idx[8];
#pragma unroll
    for (int k = 0; k < 8; k++) idx[k] = csr_src[j + k];
    float a[8];
#pragma unroll
    for (int k = 0; k < 8; k++) a[k] = __half2float(hw[(size_t)idx[k] * HIDDEN + lane]);
    acc += ((a[0] + a[1]) + (a[2] + a[3])) + ((a[4] + a[5]) + (a[6] + a[7]));
  }
  for (; j < end; j++) {
    int s = csr_src[j];
    acc += __half2float(hw[(size_t)s * HIDDEN + lane]);
  }
  float dg = (float)deg_in[wave];
  if (dg < 1.f) dg = 1.f;
  float v = acc * rsqrtf(dg) + bias[lane];
  out[(size_t)wave * HIDDEN + lane] = v > 0.f ? v : 0.f;
}

// ---------------- per-graph mean pool stage 1 (sorted node_graph, run-accumulate) ----------------
__global__ __launch_bounds__(256) void pool_k(const float* __restrict__ h,
                                              const int* __restrict__ node_graph,
                                              float* __restrict__ sums,
                                              float* __restrict__ counts) {
  const int NPW = 256;  // nodes per wave
  int wave = (int)((blockIdx.x * blockDim.x + threadIdx.x) >> 6);
  int lane = threadIdx.x & 63;
  int start = wave * NPW;
  if (start >= N_NODES) return;
  int end = start + NPW; if (end > N_NODES) end = N_NODES;
  int cur = node_graph[start];
  float acc = 0.f, cnt = 0.f;
  for (int n = start; n < end; n++) {
    int g = node_graph[n];
    if (g != cur) {
      atomicAdd(&sums[cur * HIDDEN + lane], acc);
      if (lane == 0) atomicAdd(&counts[cur], cnt);
      cur = g; acc = 0.f; cnt = 0.f;
    }
    acc += h[(size_t)n * HIDDEN + lane];
    cnt += 1.f;
  }
  atomicAdd(&sums[cur * HIDDEN + lane], acc);
  if (lane == 0) atomicAdd(&counts[cur], cnt);
}

// ---------------- final: h_graph = sums/counts; mu/logvar = h_graph @ Wmu/Wlv + b ----------------
__global__ __launch_bounds__(256) void final_k(const float* __restrict__ sums,
                                               const float* __restrict__ counts,
                                               const float* __restrict__ Wmu,
                                               const float* __restrict__ bmu,
                                               const float* __restrict__ Wlv,
                                               const float* __restrict__ blv,
                                               float* __restrict__ out) {
  __shared__ float hg[N_GRAPHS][HIDDEN];
  __shared__ float wmu[HIDDEN][LATENT];
  __shared__ float wlv[HIDDEN][LATENT];
  int t = threadIdx.x;
  for (int i = t; i < N_GRAPHS * HIDDEN; i += 256) {
    int g = i / HIDDEN;
    float c = counts[g];
    if (c < 1.f) c = 1.f;
    hg[g][i % HIDDEN] = sums[i] / c;
  }
  for (int i = t; i < HIDDEN * LATENT; i += 256) {
    wmu[i / LATENT][i % LATENT] = Wmu[i];
    wlv[i / LATENT][i % LATENT] = Wlv[i];
  }
  __syncthreads();
  for (int i = t; i < N_GRAPHS * LATENT; i += 256) {
    int g = i / LATENT, j = i % LATENT;
    float mu = bmu[j], lv = blv[j];
#pragma unroll
    for (int k = 0; k < HIDDEN; k++) {
      float v = hg[g][k];
      mu += v * wmu[k][j];
      lv += v * wlv[k][j];
    }
    out[i] = mu;
    out[N_GRAPHS * LATENT + i] = lv;
  }
}

extern "C" void kernel_launch(void* const* d_in, const int* in_sizes, int n_in,
                              void* d_out, int out_size, void* d_ws, size_t ws_size,
                              hipStream_t stream) {
  const float* x = (const float*)d_in[0];
  // d_in[1] = edge_feat: provably unused for (mu, logvar)
  const int* src = (const int*)d_in[2];
  const int* dst = (const int*)d_in[3];
  const int* node_graph = (const int*)d_in[4];
  const float* W1 = (const float*)d_in[5];
  const float* b1 = (const float*)d_in[6];
  const float* W2 = (const float*)d_in[7];
  const float* b2 = (const float*)d_in[8];
  // d_in[9] = We, d_in[10] = be: unused
  const float* Wmu = (const float*)d_in[11];
  const float* bmu = (const float*)d_in[12];
  const float* Wlv = (const float*)d_in[13];
  const float* blv = (const float*)d_in[14];
  float* out = (float*)d_out;

  char* ws = (char*)d_ws;
  // zeroed control block [0, 33280)
  int* bc_src   = (int*)(ws + 0);        // 4096
  int* bc_dst   = (int*)(ws + 4096);     // 4096
  int* cur_src  = (int*)(ws + 8192);     // 4096
  int* cur_dst  = (int*)(ws + 12288);    // 4096
  float* cnts   = (float*)(ws + 16384);  // 256 (pad 512)
  float* sums   = (float*)(ws + 16896);  // 16384
  // non-zeroed control
  int* bbase_src = (int*)(ws + 33280);   // 4100 (pad to 37632)
  int* bbase_dst = (int*)(ws + 37632);   // 4100 (pad to 41984)
  int* tbl_src   = (int*)(ws + 41984);   // 1048576
  int* tbl_dst   = (int*)(ws + 1090560); // 1048576 -> 2139136
  // big arrays
  int* deg_out = (int*)(ws + 2139136);   // 400128
  int* deg_in  = (int*)(ws + 2539264);   // 400128
  int* row_ptr = (int*)(ws + 2939392);   // 400128
  int* csr_src = (int*)(ws + 3339520);   // 12800000 -> 16139520
  int* sortedS = (int*)(ws + 16139520);  // 12800000 } dead after bucket_csr_k,
  int* sortedE = (int*)(ws + 28939520);  // 12800000 } region reused as A (fp16)
  __half* A    = (__half*)(ws + 16139520); // 12800000 (alias of sortedS)
  float* B     = (float*)(ws + 41739520); // 25600000 -> end 67339520

  zero_k<<<(33280 / 16 + 255) / 256, 256, 0, stream>>>((int4*)ws, 33280 / 16);

  bucket_hist_k<<<NBLK_PART, 256, 0, stream>>>((const int4*)src, (const int4*)dst,
                                               bc_src, bc_dst, tbl_src, tbl_dst);
  bucket_scan_k<<<1, 1024, 0, stream>>>(bc_src, bc_dst, bbase_src, bbase_dst, row_ptr);
  scatter_k<<<NBLK_PART, 256, 0, stream>>>((const int4*)src, (const int4*)dst,
                                           bbase_src, bbase_dst, tbl_src, tbl_dst,
                                           cur_src, cur_dst, sortedS, sortedE);
  bucket_csr_k<<<NB_USED, 256, 0, stream>>>(sortedS, sortedE, bbase_src, bbase_dst,
                                            deg_out, deg_in, row_ptr, csr_src);

  const int GEMM_BLKS = (N_NODES + 63) / 64;  // 1563

  // layer 1: A = fp16((x @ W1) * deg_out^-1/2) ; B = relu(agg(A) * deg_in^-1/2 + b1)
  gemm_tile_k<IN_DIM, __half><<<GEMM_BLKS, 256, 0, stream>>>(x, W1, deg_out, A);
  aggregate_k<<<(N_NODES + 3) / 4, 256, 0, stream>>>(A, row_ptr, csr_src, deg_in, b1, B);

  // layer 2: A = fp16((B @ W2) * deg_out^-1/2) ; B = relu(agg(A) * deg_in^-1/2 + b2)
  gemm_tile_k<HIDDEN, __half><<<GEMM_BLKS, 256, 0, stream>>>(B, W2, deg_out, A);
  aggregate_k<<<(N_NODES + 3) / 4, 256, 0, stream>>>(A, row_ptr, csr_src, deg_in, b2, B);

  // pool + heads
  pool_k<<<((N_NODES + 255) / 256 + 3) / 4, 256, 0, stream>>>(B, node_graph, sums, cnts);
  final_k<<<1, 256, 0, stream>>>(sums, cnts, Wmu, bmu, Wlv, blv, out);
}